// Round 18
// baseline (364.379 us; speedup 1.0000x reference)
//
#include <hip/hip_runtime.h>

#define SEQ   512
#define BATCH 256
#define DIN   128
#define XPAD  132     // x_chunk row stride: 132 ≡ 4 (mod 32) -> sp rows hit disjoint banks
#define HID   256
#define NOISE 0.99f

__device__ __forceinline__ float dot4(float4 a, float4 b) {
    return fmaf(a.x, b.x, fmaf(a.y, b.y, fmaf(a.z, b.z, a.w * b.w)));
}
// round-11 validated activations (v_rcp; error bucket unchanged vs exact div)
__device__ __forceinline__ float sigmoid_(float x) {
    return __builtin_amdgcn_rcpf(1.0f + __expf(-x));
}
__device__ __forceinline__ float tanh_(float x) {
    float ax = fabsf(x);
    float e  = __expf(2.0f * ax);
    float t  = __builtin_amdgcn_rcpf(e + 1.0f);
    float r  = 1.0f - 2.0f * t;
    return copysignf(r, x);
}
template <int CTRL>
__device__ __forceinline__ float dppmov(float v) {
    return __int_as_float(__builtin_amdgcn_mov_dpp(__float_as_int(v), CTRL, 0xF, 0xF, false));
}
__device__ __forceinline__ float swap16_sum(float v) {
    float a = v, b;
    asm("v_mov_b32 %1, %0\n\tv_permlane16_swap_b32 %0, %1" : "+v"(a), "=&v"(b));
    return a + b;
}
__device__ __forceinline__ float swap32_sum(float v) {
    float a = v, b;
    asm("v_mov_b32 %1, %0\n\tv_permlane32_swap_b32 %0, %1" : "+v"(a), "=&v"(b));
    return a + b;
}
// LDS-only barrier (no vmcnt drain) — round-10 validated
__device__ __forceinline__ void barrier_lds() {
    asm volatile("s_waitcnt lgkmcnt(0)\n\ts_barrier" ::: "memory");
}

// ---------------------------------------------------------------------------
// Fused kernel. Prologue: pre[s][p] into LDS — coalesced x staging (double-
// buffered, PADDED rows) + per-thread w-row in registers; bitwise pre_gemm
// math. Then the round-11 recurrence (bitwise) reading pre from LDS.
// ---------------------------------------------------------------------------
__global__ __launch_bounds__(256, 1) void qlstm_fused(
    const float* __restrict__ x,      // (S,B,D)
    const float* __restrict__ w_lin,  // (16,384): x-part [0:128), hx-part [128:384)
    const float* __restrict__ b_lin,  // (16,)
    const float* __restrict__ w_map,  // (4,256,4)
    const float* __restrict__ b_map,  // (4,256)
    const float* __restrict__ theta,  // (16,)
    float* __restrict__ out)
{
    const int b = blockIdx.x;
    const int t = threadIdx.x;

    __shared__ __align__(16) float pre_lds[SEQ * 16];      // 32 KB
    __shared__ __align__(16) float x_chunk[2][16][XPAD];   // 16.5 KB
    __shared__ __align__(16) float hx_lds[HID];
    __shared__ __align__(16) float acts_lds[16];

    // ================= prologue: pre[s][p], bitwise pre_gemm ===============
    const int sp = t >> 4;                // s sub-row 0..15
    const int pp = t & 15;

    // w-row in registers: same bits, same dot4 chain as the wlds path
    float4 wreg[32];
    {
        const float* wrow = w_lin + pp * 384;
        #pragma unroll
        for (int d = 0; d < 32; ++d)
            wreg[d] = *(const float4*)(wrow + d * 4);
    }
    const float bt = b_lin[pp] + theta[pp];

    const int xr_ = t >> 5;               // row 0..7 (and +8)
    const int xc_ = (t & 31) << 2;        // float col of this lane's float4
    auto xld = [&](int c, int r) -> float4 {    // coalesced: lanes span a row
        return *(const float4*)(x + ((size_t)((c << 4) + r) * BATCH + b) * DIN + xc_);
    };

    // stage chunk 0, prefetch chunk 1
    float4 ra = xld(0, xr_), rb = xld(0, xr_ + 8);
    *(float4*)&x_chunk[0][xr_][xc_]     = ra;
    *(float4*)&x_chunk[0][xr_ + 8][xc_] = rb;
    ra = xld(1, xr_); rb = xld(1, xr_ + 8);
    barrier_lds();                        // chunk0 visible

    for (int c = 0; c < 32; ++c) {
        // compute chunk c from LDS (per-sp rows on disjoint banks: no conflict)
        const float* xrow = x_chunk[c & 1][sp];
        float acc = bt;
        #pragma unroll 8
        for (int d = 0; d < 32; ++d)
            acc += dot4(*(const float4*)(xrow + d * 4), wreg[d]);
        pre_lds[((c << 4) + sp) * 16 + pp] = acc;

        // commit prefetched chunk c+1, issue loads for chunk c+2
        if (c + 1 < 32) {
            *(float4*)&x_chunk[(c + 1) & 1][xr_][xc_]     = ra;
            *(float4*)&x_chunk[(c + 1) & 1][xr_ + 8][xc_] = rb;
            if (c + 2 < 32) { ra = xld(c + 2, xr_); rb = xld(c + 2, xr_ + 8); }
        }
        barrier_lds();
    }

    // ================= recurrence: round-11 verbatim, pre from LDS =========
    const int l = t & 63;
    const int g = t >> 6;        // wave index == gate
    const int q = l & 3;
    const int j = l >> 2;        // 0..15
    const int p = (g << 2) | q;

    const int sig = (j >> 1) & 3;
    const float* wp = w_lin + p * 384 + 128 + j * 16;
    const float4 wh0 = *(const float4*)(wp + ((0 ^ sig) << 2));
    const float4 wh1 = *(const float4*)(wp + ((1 ^ sig) << 2));
    const float4 wh2 = *(const float4*)(wp + ((2 ^ sig) << 2));
    const float4 wh3 = *(const float4*)(wp + ((3 ^ sig) << 2));

    const float4 wm0 = ((const float4*)w_map)[0 * 256 + t];
    const float4 wm1 = ((const float4*)w_map)[1 * 256 + t];
    const float4 wm2 = ((const float4*)w_map)[2 * 256 + t];
    const float4 wm3 = ((const float4*)w_map)[3 * 256 + t];
    const float bm0 = b_map[t];
    const float bm1 = b_map[256 + t];
    const float bm2 = b_map[512 + t];
    const float bm3 = b_map[768 + t];

    const float* hr = &hx_lds[j * 16];
    const float* hr0 = hr + ((0 ^ sig) << 2);
    const float* hr1 = hr + ((1 ^ sig) << 2);
    const float* hr2 = hr + ((2 ^ sig) << 2);
    const float* hr3 = hr + ((3 ^ sig) << 2);

    hx_lds[t] = 0.0f;
    float hx = 0.0f, cx = 0.0f;
    float* out_seq = out;
    float* out_hx  = out + (size_t)SEQ * BATCH * HID;
    float* out_cx  = out_hx + BATCH * HID;
    barrier_lds();               // pre_lds + hx_lds visible

    float px0 = pre_lds[p];      // 1-step-ahead prefetch from LDS

    for (int s = 0; s < SEQ; ++s) {
        const float pxu = px0;
        const int s1 = (s + 1 < SEQ) ? s + 1 : SEQ - 1;
        px0 = pre_lds[s1 * 16 + p];

        // ---- phase 1: hx matvec + reduce (VALU comms) + quantum + act ------
        const float4 ha0 = *(const float4*)hr0;
        const float4 ha1 = *(const float4*)hr1;
        const float4 ha2 = *(const float4*)hr2;
        const float4 ha3 = *(const float4*)hr3;
        float acc = dot4(wh0, ha0) + dot4(wh1, ha1)
                  + dot4(wh2, ha2) + dot4(wh3, ha3);
        acc += dppmov<0x124>(acc);   // += lane+4  (row_ror:4)
        acc += dppmov<0x128>(acc);   // += lane+8  (row_ror:8)
        acc  = swap16_sum(acc);      // += lane^16
        acc  = swap32_sum(acc);      // += lane^32

        const float A  = __cosf(acc + pxu);      // pre includes b_lin + theta
        const float Bv = dppmov<0xB1>(A);        // quad_perm xor1 -> C_{q^1}
        const float Cv = dppmov<0x4E>(A);        // quad_perm xor2 -> C_{q^2}
        const float Dv = dppmov<0x4E>(Bv);       //                -> C_{q^3}

        const float t1 = Cv * Dv;
        const float u  = (q & 1) ? (A * Bv) : ((q == 2) ? A : Bv);
        const float v  = (q == 1) ? 1.0f : t1;
        const float ez = NOISE * u * v;
        const float act = (g == 2) ? tanh_(ez) : sigmoid_(ez);
        if (l < 4) acts_lds[(g << 2) | l] = act;
        barrier_lds();                            // B1: acts visible (LDS only)

        // ---- phase 2: gate matvec + cell update ---------------------------
        const float4 a0 = *(const float4*)&acts_lds[0];
        const float4 a1 = *(const float4*)&acts_lds[4];
        const float4 a2 = *(const float4*)&acts_lds[8];
        const float4 a3 = *(const float4*)&acts_lds[12];

        const float fv = bm0 + dot4(wm0, a0);
        const float iv = bm1 + dot4(wm1, a1);
        const float gv = bm2 + dot4(wm2, a2);
        const float ov = bm3 + dot4(wm3, a3);

        cx = fmaf(fv, cx, iv * gv);
        hx = ov * tanh_(cx);

        hx_lds[t] = hx;
        out_seq[((size_t)s * BATCH + b) * HID + t] = hx;
        barrier_lds();                            // B2: hx visible (LDS only)
    }

    out_hx[(size_t)b * HID + t] = hx;
    out_cx[(size_t)b * HID + t] = cx;
}

extern "C" void kernel_launch(void* const* d_in, const int* in_sizes, int n_in,
                              void* d_out, int out_size, void* d_ws, size_t ws_size,
                              hipStream_t stream) {
    const float* x     = (const float*)d_in[0];
    const float* w_lin = (const float*)d_in[1];
    const float* b_lin = (const float*)d_in[2];
    const float* w_map = (const float*)d_in[3];
    const float* b_map = (const float*)d_in[4];
    const float* theta = (const float*)d_in[5];
    float* out = (float*)d_out;

    qlstm_fused<<<dim3(BATCH), dim3(256), 0, stream>>>(
        x, w_lin, b_lin, w_map, b_map, theta, out);
}

// Round 19
// 250.951 us; speedup vs baseline: 1.4520x; 1.4520x over previous
//
#include <hip/hip_runtime.h>

#define SEQ   512
#define BATCH 256
#define DIN   128
#define XPAD  132     // x_chunk row stride: 132 ≡ 4 (mod 32) -> sp rows hit disjoint banks
#define HID   256
#define NOISE 0.99f

__device__ __forceinline__ float dot4(float4 a, float4 b) {
    return fmaf(a.x, b.x, fmaf(a.y, b.y, fmaf(a.z, b.z, a.w * b.w)));
}
// round-11 validated activations (v_rcp; error bucket unchanged vs exact div)
__device__ __forceinline__ float sigmoid_(float x) {
    return __builtin_amdgcn_rcpf(1.0f + __expf(-x));
}
__device__ __forceinline__ float tanh_(float x) {
    float ax = fabsf(x);
    float e  = __expf(2.0f * ax);
    float t  = __builtin_amdgcn_rcpf(e + 1.0f);
    float r  = 1.0f - 2.0f * t;
    return copysignf(r, x);
}
template <int CTRL>
__device__ __forceinline__ float dppmov(float v) {
    return __int_as_float(__builtin_amdgcn_mov_dpp(__float_as_int(v), CTRL, 0xF, 0xF, false));
}
__device__ __forceinline__ float swap16_sum(float v) {
    float a = v, b;
    asm("v_mov_b32 %1, %0\n\tv_permlane16_swap_b32 %0, %1" : "+v"(a), "=&v"(b));
    return a + b;
}
__device__ __forceinline__ float swap32_sum(float v) {
    float a = v, b;
    asm("v_mov_b32 %1, %0\n\tv_permlane32_swap_b32 %0, %1" : "+v"(a), "=&v"(b));
    return a + b;
}
// LDS-only barrier (no vmcnt drain) — round-10 validated
__device__ __forceinline__ void barrier_lds() {
    asm volatile("s_waitcnt lgkmcnt(0)\n\ts_barrier" ::: "memory");
}

// ---------------------------------------------------------------------------
// Fused kernel = round-17 structure (w in LDS: 2-way aliasing only, free)
// with the x_chunk rows PADDED to 132 floats (kills the 4-way sp-row bank
// conflict that cost ~7 µs/block in r17). NO per-thread weight arrays —
// r18 proved they spill to scratch (FETCH 33->284 MB). Bitwise r11 numerics.
// ---------------------------------------------------------------------------
__global__ __launch_bounds__(256, 1) void qlstm_fused(
    const float* __restrict__ x,      // (S,B,D)
    const float* __restrict__ w_lin,  // (16,384): x-part [0:128), hx-part [128:384)
    const float* __restrict__ b_lin,  // (16,)
    const float* __restrict__ w_map,  // (4,256,4)
    const float* __restrict__ b_map,  // (4,256)
    const float* __restrict__ theta,  // (16,)
    float* __restrict__ out)
{
    const int b = blockIdx.x;
    const int t = threadIdx.x;

    __shared__ __align__(16) float pre_lds[SEQ * 16];      // 32 KB
    __shared__ __align__(16) float wlds[16 * 132];         // 8.25 KB
    __shared__ __align__(16) float x_chunk[2][16][XPAD];   // 16.5 KB
    __shared__ __align__(16) float hx_lds[HID];
    __shared__ __align__(16) float acts_lds[16];

    // ================= prologue: pre[s][p], bitwise pre_gemm ===============
    for (int i = t; i < 16 * 128; i += 256) {
        int pp = i >> 7, dd = i & 127;
        wlds[pp * 132 + dd] = w_lin[pp * 384 + dd];
    }

    const int xr_ = t >> 5;               // row 0..7 (and +8)
    const int xc_ = (t & 31) << 2;        // float col of this lane's float4
    auto xld = [&](int c, int r) -> float4 {    // coalesced: lanes span a row
        return *(const float4*)(x + ((size_t)((c << 4) + r) * BATCH + b) * DIN + xc_);
    };

    // stage chunk 0, prefetch chunk 1
    float4 ra = xld(0, xr_), rb = xld(0, xr_ + 8);
    *(float4*)&x_chunk[0][xr_][xc_]     = ra;
    *(float4*)&x_chunk[0][xr_ + 8][xc_] = rb;
    ra = xld(1, xr_); rb = xld(1, xr_ + 8);
    barrier_lds();                        // wlds + chunk0 visible

    const int sp = t >> 4;                // s sub-row 0..15
    const int pp = t & 15;
    const float* wr = &wlds[pp * 132];
    const float bt = b_lin[pp] + theta[pp];

    for (int c = 0; c < 32; ++c) {
        // compute chunk c from LDS (padded rows: conflict-free x reads)
        const float* xrow = x_chunk[c & 1][sp];
        float acc = bt;
        #pragma unroll 8
        for (int d = 0; d < 32; ++d)
            acc += dot4(*(const float4*)(xrow + d * 4), *(const float4*)(wr + d * 4));
        pre_lds[((c << 4) + sp) * 16 + pp] = acc;

        // commit prefetched chunk c+1, issue loads for chunk c+2
        if (c + 1 < 32) {
            *(float4*)&x_chunk[(c + 1) & 1][xr_][xc_]     = ra;
            *(float4*)&x_chunk[(c + 1) & 1][xr_ + 8][xc_] = rb;
            if (c + 2 < 32) { ra = xld(c + 2, xr_); rb = xld(c + 2, xr_ + 8); }
        }
        barrier_lds();
    }

    // ================= recurrence: round-11 verbatim, pre from LDS =========
    const int l = t & 63;
    const int g = t >> 6;        // wave index == gate
    const int q = l & 3;
    const int j = l >> 2;        // 0..15
    const int p = (g << 2) | q;

    const int sig = (j >> 1) & 3;
    const float* wp = w_lin + p * 384 + 128 + j * 16;
    const float4 wh0 = *(const float4*)(wp + ((0 ^ sig) << 2));
    const float4 wh1 = *(const float4*)(wp + ((1 ^ sig) << 2));
    const float4 wh2 = *(const float4*)(wp + ((2 ^ sig) << 2));
    const float4 wh3 = *(const float4*)(wp + ((3 ^ sig) << 2));

    const float4 wm0 = ((const float4*)w_map)[0 * 256 + t];
    const float4 wm1 = ((const float4*)w_map)[1 * 256 + t];
    const float4 wm2 = ((const float4*)w_map)[2 * 256 + t];
    const float4 wm3 = ((const float4*)w_map)[3 * 256 + t];
    const float bm0 = b_map[t];
    const float bm1 = b_map[256 + t];
    const float bm2 = b_map[512 + t];
    const float bm3 = b_map[768 + t];

    const float* hr = &hx_lds[j * 16];
    const float* hr0 = hr + ((0 ^ sig) << 2);
    const float* hr1 = hr + ((1 ^ sig) << 2);
    const float* hr2 = hr + ((2 ^ sig) << 2);
    const float* hr3 = hr + ((3 ^ sig) << 2);

    hx_lds[t] = 0.0f;
    float hx = 0.0f, cx = 0.0f;
    float* out_seq = out;
    float* out_hx  = out + (size_t)SEQ * BATCH * HID;
    float* out_cx  = out_hx + BATCH * HID;
    barrier_lds();               // pre_lds + hx_lds visible

    float px0 = pre_lds[p];      // 1-step-ahead prefetch from LDS

    for (int s = 0; s < SEQ; ++s) {
        const float pxu = px0;
        const int s1 = (s + 1 < SEQ) ? s + 1 : SEQ - 1;
        px0 = pre_lds[s1 * 16 + p];

        // ---- phase 1: hx matvec + reduce (VALU comms) + quantum + act ------
        const float4 ha0 = *(const float4*)hr0;
        const float4 ha1 = *(const float4*)hr1;
        const float4 ha2 = *(const float4*)hr2;
        const float4 ha3 = *(const float4*)hr3;
        float acc = dot4(wh0, ha0) + dot4(wh1, ha1)
                  + dot4(wh2, ha2) + dot4(wh3, ha3);
        acc += dppmov<0x124>(acc);   // += lane+4  (row_ror:4)
        acc += dppmov<0x128>(acc);   // += lane+8  (row_ror:8)
        acc  = swap16_sum(acc);      // += lane^16
        acc  = swap32_sum(acc);      // += lane^32

        const float A  = __cosf(acc + pxu);      // pre includes b_lin + theta
        const float Bv = dppmov<0xB1>(A);        // quad_perm xor1 -> C_{q^1}
        const float Cv = dppmov<0x4E>(A);        // quad_perm xor2 -> C_{q^2}
        const float Dv = dppmov<0x4E>(Bv);       //                -> C_{q^3}

        const float t1 = Cv * Dv;
        const float u  = (q & 1) ? (A * Bv) : ((q == 2) ? A : Bv);
        const float v  = (q == 1) ? 1.0f : t1;
        const float ez = NOISE * u * v;
        const float act = (g == 2) ? tanh_(ez) : sigmoid_(ez);
        if (l < 4) acts_lds[(g << 2) | l] = act;
        barrier_lds();                            // B1: acts visible (LDS only)

        // ---- phase 2: gate matvec + cell update ---------------------------
        const float4 a0 = *(const float4*)&acts_lds[0];
        const float4 a1 = *(const float4*)&acts_lds[4];
        const float4 a2 = *(const float4*)&acts_lds[8];
        const float4 a3 = *(const float4*)&acts_lds[12];

        const float fv = bm0 + dot4(wm0, a0);
        const float iv = bm1 + dot4(wm1, a1);
        const float gv = bm2 + dot4(wm2, a2);
        const float ov = bm3 + dot4(wm3, a3);

        cx = fmaf(fv, cx, iv * gv);
        hx = ov * tanh_(cx);

        hx_lds[t] = hx;
        out_seq[((size_t)s * BATCH + b) * HID + t] = hx;
        barrier_lds();                            // B2: hx visible (LDS only)
    }

    out_hx[(size_t)b * HID + t] = hx;
    out_cx[(size_t)b * HID + t] = cx;
}

extern "C" void kernel_launch(void* const* d_in, const int* in_sizes, int n_in,
                              void* d_out, int out_size, void* d_ws, size_t ws_size,
                              hipStream_t stream) {
    const float* x     = (const float*)d_in[0];
    const float* w_lin = (const float*)d_in[1];
    const float* b_lin = (const float*)d_in[2];
    const float* w_map = (const float*)d_in[3];
    const float* b_map = (const float*)d_in[4];
    const float* theta = (const float*)d_in[5];
    float* out = (float*)d_out;

    qlstm_fused<<<dim3(BATCH), dim3(256), 0, stream>>>(
        x, w_lin, b_lin, w_map, b_map, theta, out);
}